// Round 5
// baseline (194.668 us; speedup 1.0000x reference)
//
#include <hip/hip_runtime.h>

#define N_GROUPS 4096
#define K_POS 4
#define HID 256
#define M_NEG 256
#define KDIM 768  // (K_POS-1)*HID
#define N_EMB (N_GROUPS * K_POS)

typedef __attribute__((ext_vector_type(8))) short bf16x8;
typedef __attribute__((ext_vector_type(4))) float f32x4;
typedef __attribute__((ext_vector_type(4))) uint u32x4;

__device__ inline ushort f2bf(float f) {
  uint x = __float_as_uint(f);
  return (ushort)((x + 0x7fffu + ((x >> 16) & 1u)) >> 16);
}
__device__ inline float bf2f(ushort u) { return __uint_as_float(((uint)u) << 16); }

// dot of 8 bf16 (packed in u32x4) with 8 f32 p[0..7], accumulated into acc
__device__ inline void fma8(const u32x4 a, const float* __restrict__ p, float& acc) {
#pragma unroll
  for (int d = 0; d < 4; ++d) {
    const uint u = a[d];
    acc = fmaf(__uint_as_float(u << 16), p[2 * d], acc);
    acc = fmaf(__uint_as_float(u & 0xffff0000u), p[2 * d + 1], acc);
  }
}

// ---------------- Kernel 0: fp32 -> bf16 for emb and W ----------------
#define N4_EMB (N_EMB * HID / 4)
#define N4_W   (KDIM * HID / 4)
__global__ __launch_bounds__(256) void to_bf16(
    const float* __restrict__ emb, const float* __restrict__ W,
    ushort* __restrict__ embB, ushort* __restrict__ WB) {
  const int i = blockIdx.x * 256 + threadIdx.x;
  if (i < N4_EMB) {
    const float4 v = ((const float4*)emb)[i];
    ushort4 o = {f2bf(v.x), f2bf(v.y), f2bf(v.z), f2bf(v.w)};
    ((ushort4*)embB)[i] = o;
  } else if (i < N4_EMB + N4_W) {
    const int j = i - N4_EMB;
    const float4 v = ((const float4*)W)[j];
    ushort4 o = {f2bf(v.x), f2bf(v.y), f2bf(v.z), f2bf(v.w)};
    ((ushort4*)WB)[j] = o;
  }
}

// ---------------- Kernel 1: predicts = hist_x @ W^T + b (MFMA, f32 out) ----------------
__global__ __launch_bounds__(256) void gemm_mfma(
    const ushort* __restrict__ embB, const ushort* __restrict__ WB,
    const float* __restrict__ bias, float* __restrict__ pred) {
  const int wv = threadIdx.x >> 6, l = threadIdx.x & 63;
  const int mt = blockIdx.x * 4 + wv;
  const int bn = blockIdx.y * 64;
  const int r = l & 15, g = l >> 4;

  const short* A = (const short*)embB + (size_t)(mt * 16 + r) * (K_POS * HID) + g * 8;
  f32x4 acc[4] = {{0,0,0,0},{0,0,0,0},{0,0,0,0},{0,0,0,0}};
  for (int k0 = 0; k0 < KDIM; k0 += 32) {
    const bf16x8 a = *(const bf16x8*)(A + k0);
#pragma unroll
    for (int j = 0; j < 4; ++j) {
      const bf16x8 b = *(const bf16x8*)((const short*)WB + (size_t)(bn + j * 16 + r) * KDIM + g * 8 + k0);
      acc[j] = __builtin_amdgcn_mfma_f32_16x16x32_bf16(a, b, acc[j], 0, 0, 0);
    }
  }
#pragma unroll
  for (int j = 0; j < 4; ++j) {
    const int col = bn + j * 16 + r;
    const float bb = bias[col];
#pragma unroll
    for (int i = 0; i < 4; ++i)
      pred[(size_t)(mt * 16 + g * 4 + i) * HID + col] = acc[j][i] + bb;
  }
}

// ---------------- Kernel 2: per-row loss; wave owns HALF a row (128 negs, 2/lane) ----
// block = 4 waves = 2 rows; grid = 2048 blocks -> 8 blocks/CU -> 32 waves/CU target.
__global__ __launch_bounds__(256) void loss_rows(
    const ushort* __restrict__ embB, const float* __restrict__ pred,
    const int* __restrict__ neg_perm, float* __restrict__ row_loss) {
  const int tid = threadIdx.x;
  const int lane = tid & 63, wv = tid >> 6;
  const int w = blockIdx.x * 4 + wv;
  const int n = w >> 1, half = w & 1;
  __shared__ float smax[4], ssum[4], spos[4];

  // positive logit: computed by the even (half==0) wave of each row
  float posv = 0.f;
  if (half == 0) {
    const ushort4 h = *(const ushort4*)(embB + ((size_t)n * K_POS + K_POS - 1) * HID + lane * 4);
    const float4 pv = *(const float4*)(pred + (size_t)n * HID + lane * 4);
    float s = bf2f(h.x) * pv.x + bf2f(h.y) * pv.y + bf2f(h.z) * pv.z + bf2f(h.w) * pv.w;
    s += __shfl_xor(s, 1);  s += __shfl_xor(s, 2);  s += __shfl_xor(s, 4);
    s += __shfl_xor(s, 8);  s += __shfl_xor(s, 16); s += __shfl_xor(s, 32);
    posv = s;
  }

  // lane owns 2 negatives of this half-row
  const int2 raw = *(const int2*)(neg_perm + (size_t)n * M_NEG + half * 128 + lane * 2);
  const int base = n * K_POS;
  const ushort* rp0 = embB + (size_t)(raw.x + (raw.x >= base ? K_POS : 0)) * HID;
  const ushort* rp1 = embB + (size_t)(raw.y + (raw.y >= base ? K_POS : 0)) * HID;

  const float4* gp = (const float4*)(pred + (size_t)n * HID);  // wave-uniform

  float ac0 = 0.f, ac1 = 0.f;
#pragma unroll 1
  for (int c = 0; c < HID; c += 32) {
    u32x4 a0[4], a1[4];
#pragma unroll
    for (int q = 0; q < 4; ++q) {
      a0[q] = *(const u32x4*)(rp0 + c + 8 * q);
      a1[q] = *(const u32x4*)(rp1 + c + 8 * q);
    }
#pragma unroll
    for (int q = 0; q < 4; ++q) {
      const float4 v0 = gp[c / 4 + 2 * q];
      const float4 v1 = gp[c / 4 + 2 * q + 1];
      const float p[8] = {v0.x, v0.y, v0.z, v0.w, v1.x, v1.y, v1.z, v1.w};
      fma8(a0[q], p, ac0);
      fma8(a1[q], p, ac1);
    }
  }

  // wave-level partial max / sumexp over this half-row
  float mx = fmaxf(ac0, ac1);
  mx = fmaxf(mx, __shfl_xor(mx, 1));  mx = fmaxf(mx, __shfl_xor(mx, 2));
  mx = fmaxf(mx, __shfl_xor(mx, 4));  mx = fmaxf(mx, __shfl_xor(mx, 8));
  mx = fmaxf(mx, __shfl_xor(mx, 16)); mx = fmaxf(mx, __shfl_xor(mx, 32));

  float se = __expf(ac0 - mx) + __expf(ac1 - mx);
  se += __shfl_xor(se, 1);  se += __shfl_xor(se, 2);  se += __shfl_xor(se, 4);
  se += __shfl_xor(se, 8);  se += __shfl_xor(se, 16); se += __shfl_xor(se, 32);

  if (lane == 0) {
    smax[wv] = mx;
    ssum[wv] = se;
    spos[wv] = posv;
  }
  __syncthreads();

  // even wave of each row combines the two halves
  if ((half == 0) && lane == 0) {
    const float m0 = smax[wv], m1 = smax[wv + 1];
    const float s0 = ssum[wv], s1 = ssum[wv + 1];
    const float pv = spos[wv];
    const float m = fmaxf(fmaxf(m0, m1), pv);
    const float tot = s0 * __expf(m0 - m) + s1 * __expf(m1 - m) + __expf(pv - m);
    row_loss[n] = __logf(tot) + m - pv;
  }
}

// ---------------- Kernel 3: deterministic mean ----------------
__global__ __launch_bounds__(256) void reduce_mean(
    const float* __restrict__ row_loss, float* __restrict__ out) {
  const int tid = threadIdx.x;
  const int lane = tid & 63, wv = tid >> 6;
  float s = 0.f;
  for (int i = tid; i < N_GROUPS; i += 256) s += row_loss[i];
  s += __shfl_xor(s, 1);  s += __shfl_xor(s, 2);  s += __shfl_xor(s, 4);
  s += __shfl_xor(s, 8);  s += __shfl_xor(s, 16); s += __shfl_xor(s, 32);
  __shared__ float red[4];
  if (lane == 0) red[wv] = s;
  __syncthreads();
  if (tid == 0) out[0] = (red[0] + red[1] + red[2] + red[3]) * (1.0f / N_GROUPS);
}

extern "C" void kernel_launch(void* const* d_in, const int* in_sizes, int n_in,
                              void* d_out, int out_size, void* d_ws, size_t ws_size,
                              hipStream_t stream) {
  const float* emb = (const float*)d_in[0];
  const float* W = (const float*)d_in[1];
  const float* b = (const float*)d_in[2];
  const int* neg_perm = (const int*)d_in[4];
  float* out = (float*)d_out;

  ushort* embB = (ushort*)d_ws;                              // 8 MB
  ushort* WB = embB + (size_t)N_EMB * HID;                   // 0.4 MB
  float* pred = (float*)(WB + (size_t)KDIM * HID);           // 4 MB (f32)
  float* row_loss = pred + (size_t)N_GROUPS * HID;           // 16 KB

  const int n4 = N4_EMB + N4_W;
  to_bf16<<<(n4 + 255) / 256, 256, 0, stream>>>(emb, W, embB, WB);
  gemm_mfma<<<dim3(N_GROUPS / 64, HID / 64), 256, 0, stream>>>(embB, WB, b, pred);
  loss_rows<<<N_GROUPS / 2, 256, 0, stream>>>(embB, pred, neg_perm, row_loss);
  reduce_mean<<<1, 256, 0, stream>>>(row_loss, out);
}

// Round 6
// 95.210 us; speedup vs baseline: 2.0446x; 2.0446x over previous
//
#include <hip/hip_runtime.h>

#define N_GROUPS 4096
#define K_POS 4
#define HID 256
#define M_NEG 256
#define KDIM 768  // (K_POS-1)*HID
#define N_EMB (N_GROUPS * K_POS)

typedef __attribute__((ext_vector_type(8))) short bf16x8;
typedef __attribute__((ext_vector_type(4))) float f32x4;

__device__ inline ushort f2bf(float f) {
  uint x = __float_as_uint(f);
  return (ushort)((x + 0x7fffu + ((x >> 16) & 1u)) >> 16);
}
__device__ inline float bf2f(ushort u) { return __uint_as_float(((uint)u) << 16); }

// ---------------- Kernel 0: fp32 -> bf16 for emb and W ----------------
#define N4_EMB (N_EMB * HID / 4)
#define N4_W   (KDIM * HID / 4)
__global__ __launch_bounds__(256) void to_bf16(
    const float* __restrict__ emb, const float* __restrict__ W,
    ushort* __restrict__ embB, ushort* __restrict__ WB) {
  const int i = blockIdx.x * 256 + threadIdx.x;
  if (i < N4_EMB) {
    const float4 v = ((const float4*)emb)[i];
    ushort4 o = {f2bf(v.x), f2bf(v.y), f2bf(v.z), f2bf(v.w)};
    ((ushort4*)embB)[i] = o;
  } else if (i < N4_EMB + N4_W) {
    const int j = i - N4_EMB;
    const float4 v = ((const float4*)W)[j];
    ushort4 o = {f2bf(v.x), f2bf(v.y), f2bf(v.z), f2bf(v.w)};
    ((ushort4*)WB)[j] = o;
  }
}

// ---------------- Kernel 1: predicts = hist_x @ W^T + b (MFMA, bf16 out) ---------
__global__ __launch_bounds__(256) void gemm_mfma(
    const ushort* __restrict__ embB, const ushort* __restrict__ WB,
    const float* __restrict__ bias, ushort* __restrict__ predB) {
  const int wv = threadIdx.x >> 6, l = threadIdx.x & 63;
  const int mt = blockIdx.x * 4 + wv;
  const int bn = blockIdx.y * 64;
  const int r = l & 15, g = l >> 4;

  const short* A = (const short*)embB + (size_t)(mt * 16 + r) * (K_POS * HID) + g * 8;
  f32x4 acc[4] = {{0,0,0,0},{0,0,0,0},{0,0,0,0},{0,0,0,0}};
  for (int k0 = 0; k0 < KDIM; k0 += 32) {
    const bf16x8 a = *(const bf16x8*)(A + k0);
#pragma unroll
    for (int j = 0; j < 4; ++j) {
      const bf16x8 b = *(const bf16x8*)((const short*)WB + (size_t)(bn + j * 16 + r) * KDIM + g * 8 + k0);
      acc[j] = __builtin_amdgcn_mfma_f32_16x16x32_bf16(a, b, acc[j], 0, 0, 0);
    }
  }
  // C/D: col = lane&15, row = (lane>>4)*4 + i
#pragma unroll
  for (int j = 0; j < 4; ++j) {
    const int col = bn + j * 16 + r;
    const float bb = bias[col];
#pragma unroll
    for (int i = 0; i < 4; ++i)
      predB[(size_t)(mt * 16 + g * 4 + i) * HID + col] = f2bf(acc[j][i] + bb);
  }
}

// ---------------- Kernel 2: negative logits via MFMA (line-coalesced gather) ------
// Wave owns row n. Per 16-negative tile jt: B-fragment lane l = row idx[jt*16+(l&15)],
// k-chunk (l>>4)*8; lanes {j,j+16,j+32,j+48} cover one 64B line -> 16 lines/instr.
// A = pred row replicated over the 16 M-rows. C: lane l holds logit of neg jt*16+(l&15)
// (4 identical regs). Online-lse in 2 chains; each negative appears in 4 lanes -> /4.
__global__ __launch_bounds__(256) void loss_mfma(
    const ushort* __restrict__ embB, const ushort* __restrict__ predB,
    const int* __restrict__ neg_perm, float* __restrict__ row_loss) {
  const int tid = threadIdx.x;
  const int lane = tid & 63, wv = tid >> 6;
  const int n = blockIdx.x * 4 + wv;
  const int jl = lane & 15, g = lane >> 4;
  const int base = n * K_POS;

  // A fragment: predB row n (same for all 16 M-rows)
  bf16x8 a[8];
  {
    const short* ap = (const short*)predB + (size_t)n * HID + g * 8;
#pragma unroll
    for (int kk = 0; kk < 8; ++kk) a[kk] = *(const bf16x8*)(ap + kk * 32);
  }

  // positive logit (one butterfly)
  float posv;
  {
    const ushort4 h = *(const ushort4*)(embB + ((size_t)n * K_POS + K_POS - 1) * HID + lane * 4);
    const ushort4 p = *(const ushort4*)(predB + (size_t)n * HID + lane * 4);
    float s = bf2f(h.x) * bf2f(p.x) + bf2f(h.y) * bf2f(p.y) +
              bf2f(h.z) * bf2f(p.z) + bf2f(h.w) * bf2f(p.w);
    s += __shfl_xor(s, 1);  s += __shfl_xor(s, 2);  s += __shfl_xor(s, 4);
    s += __shfl_xor(s, 8);  s += __shfl_xor(s, 16); s += __shfl_xor(s, 32);
    posv = s;
  }

  const int* nb = neg_perm + (size_t)n * M_NEG;
  float m0 = -INFINITY, s0 = 0.f, m1 = -INFINITY, s1 = 0.f;

#pragma unroll 1
  for (int jt = 0; jt < 16; jt += 2) {
    int j0 = nb[jt * 16 + jl];      j0 += (j0 >= base) ? K_POS : 0;
    int j1 = nb[jt * 16 + 16 + jl]; j1 += (j1 >= base) ? K_POS : 0;
    const short* bp0 = (const short*)embB + (size_t)j0 * HID + g * 8;
    const short* bp1 = (const short*)embB + (size_t)j1 * HID + g * 8;
    f32x4 acc0 = {0.f, 0.f, 0.f, 0.f}, acc1 = {0.f, 0.f, 0.f, 0.f};
#pragma unroll
    for (int kk = 0; kk < 8; ++kk) {
      const bf16x8 b0 = *(const bf16x8*)(bp0 + kk * 32);
      acc0 = __builtin_amdgcn_mfma_f32_16x16x32_bf16(a[kk], b0, acc0, 0, 0, 0);
    }
#pragma unroll
    for (int kk = 0; kk < 8; ++kk) {
      const bf16x8 b1 = *(const bf16x8*)(bp1 + kk * 32);
      acc1 = __builtin_amdgcn_mfma_f32_16x16x32_bf16(a[kk], b1, acc1, 0, 0, 0);
    }
    const float v0 = acc0[0], v1 = acc1[0];
    { const float mn = fmaxf(m0, v0); s0 = s0 * __expf(m0 - mn) + __expf(v0 - mn); m0 = mn; }
    { const float mn = fmaxf(m1, v1); s1 = s1 * __expf(m1 - mn) + __expf(v1 - mn); m1 = mn; }
  }

  // merge the two chains
  float m = fmaxf(m0, m1);
  float s = s0 * __expf(m0 - m) + s1 * __expf(m1 - m);

  // wave logsumexp: butterfly max, then rescaled sum
  float gm = m;
  gm = fmaxf(gm, __shfl_xor(gm, 1));  gm = fmaxf(gm, __shfl_xor(gm, 2));
  gm = fmaxf(gm, __shfl_xor(gm, 4));  gm = fmaxf(gm, __shfl_xor(gm, 8));
  gm = fmaxf(gm, __shfl_xor(gm, 16)); gm = fmaxf(gm, __shfl_xor(gm, 32));
  float sr = s * __expf(m - gm);
  sr += __shfl_xor(sr, 1);  sr += __shfl_xor(sr, 2);  sr += __shfl_xor(sr, 4);
  sr += __shfl_xor(sr, 8);  sr += __shfl_xor(sr, 16); sr += __shfl_xor(sr, 32);
  sr *= 0.25f;  // every negative counted by 4 lanes

  if (lane == 0) {
    const float gm2 = fmaxf(gm, posv);
    const float tot = sr * __expf(gm - gm2) + __expf(posv - gm2);
    row_loss[n] = __logf(tot) + gm2 - posv;
  }
}

// ---------------- Kernel 3: deterministic mean ----------------
__global__ __launch_bounds__(256) void reduce_mean(
    const float* __restrict__ row_loss, float* __restrict__ out) {
  const int tid = threadIdx.x;
  const int lane = tid & 63, wv = tid >> 6;
  float s = 0.f;
  for (int i = tid; i < N_GROUPS; i += 256) s += row_loss[i];
  s += __shfl_xor(s, 1);  s += __shfl_xor(s, 2);  s += __shfl_xor(s, 4);
  s += __shfl_xor(s, 8);  s += __shfl_xor(s, 16); s += __shfl_xor(s, 32);
  __shared__ float red[4];
  if (lane == 0) red[wv] = s;
  __syncthreads();
  if (tid == 0) out[0] = (red[0] + red[1] + red[2] + red[3]) * (1.0f / N_GROUPS);
}

extern "C" void kernel_launch(void* const* d_in, const int* in_sizes, int n_in,
                              void* d_out, int out_size, void* d_ws, size_t ws_size,
                              hipStream_t stream) {
  const float* emb = (const float*)d_in[0];
  const float* W = (const float*)d_in[1];
  const float* b = (const float*)d_in[2];
  const int* neg_perm = (const int*)d_in[4];
  float* out = (float*)d_out;

  ushort* embB = (ushort*)d_ws;                              // 8.4 MB
  ushort* WB = embB + (size_t)N_EMB * HID;                   // 0.4 MB
  ushort* predB = WB + (size_t)KDIM * HID;                   // 2.1 MB
  float* row_loss = (float*)(predB + (size_t)N_GROUPS * HID);

  const int n4 = N4_EMB + N4_W;
  to_bf16<<<(n4 + 255) / 256, 256, 0, stream>>>(emb, W, embB, WB);
  gemm_mfma<<<dim3(N_GROUPS / 64, HID / 64), 256, 0, stream>>>(embB, WB, b, predB);
  loss_mfma<<<N_GROUPS / 4, 256, 0, stream>>>(embB, predB, neg_perm, row_loss);
  reduce_mean<<<1, 256, 0, stream>>>(row_loss, out);
}

// Round 7
// 94.921 us; speedup vs baseline: 2.0509x; 1.0030x over previous
//
#include <hip/hip_runtime.h>

#define N_GROUPS 4096
#define K_POS 4
#define HID 256
#define M_NEG 256
#define KDIM 768  // (K_POS-1)*HID
#define N_EMB (N_GROUPS * K_POS)

typedef __attribute__((ext_vector_type(8))) short bf16x8;
typedef __attribute__((ext_vector_type(4))) float f32x4;

__device__ inline ushort f2bf(float f) {
  uint x = __float_as_uint(f);
  return (ushort)((x + 0x7fffu + ((x >> 16) & 1u)) >> 16);
}
__device__ inline float bf2f(ushort u) { return __uint_as_float(((uint)u) << 16); }

// ---------------- Kernel 0: fp32 -> bf16 for emb and W ----------------
#define N4_EMB (N_EMB * HID / 4)
#define N4_W   (KDIM * HID / 4)
__global__ __launch_bounds__(256) void to_bf16(
    const float* __restrict__ emb, const float* __restrict__ W,
    ushort* __restrict__ embB, ushort* __restrict__ WB) {
  const int i = blockIdx.x * 256 + threadIdx.x;
  if (i < N4_EMB) {
    const float4 v = ((const float4*)emb)[i];
    ushort4 o = {f2bf(v.x), f2bf(v.y), f2bf(v.z), f2bf(v.w)};
    ((ushort4*)embB)[i] = o;
  } else if (i < N4_EMB + N4_W) {
    const int j = i - N4_EMB;
    const float4 v = ((const float4*)W)[j];
    ushort4 o = {f2bf(v.x), f2bf(v.y), f2bf(v.z), f2bf(v.w)};
    ((ushort4*)WB)[j] = o;
  }
}

// ---------------- Kernel 1: predicts = hist_x @ W^T + b (MFMA, bf16 out) ---------
__global__ __launch_bounds__(256) void gemm_mfma(
    const ushort* __restrict__ embB, const ushort* __restrict__ WB,
    const float* __restrict__ bias, ushort* __restrict__ predB) {
  const int wv = threadIdx.x >> 6, l = threadIdx.x & 63;
  const int mt = blockIdx.x * 4 + wv;
  const int bn = blockIdx.y * 64;
  const int r = l & 15, g = l >> 4;

  const short* A = (const short*)embB + (size_t)(mt * 16 + r) * (K_POS * HID) + g * 8;
  f32x4 acc[4] = {{0,0,0,0},{0,0,0,0},{0,0,0,0},{0,0,0,0}};
  for (int k0 = 0; k0 < KDIM; k0 += 32) {
    const bf16x8 a = *(const bf16x8*)(A + k0);
#pragma unroll
    for (int j = 0; j < 4; ++j) {
      const bf16x8 b = *(const bf16x8*)((const short*)WB + (size_t)(bn + j * 16 + r) * KDIM + g * 8 + k0);
      acc[j] = __builtin_amdgcn_mfma_f32_16x16x32_bf16(a, b, acc[j], 0, 0, 0);
    }
  }
  // C/D: col = lane&15, row = (lane>>4)*4 + i
#pragma unroll
  for (int j = 0; j < 4; ++j) {
    const int col = bn + j * 16 + r;
    const float bb = bias[col];
#pragma unroll
    for (int i = 0; i < 4; ++i)
      predB[(size_t)(mt * 16 + g * 4 + i) * HID + col] = f2bf(acc[j][i] + bb);
  }
}

// ---------------- Kernel 2: negative logits via MFMA, 2 waves per row ------------
// Wave owns half a row (128 negs = 8 tiles of 16). B-fragment lane l: row
// idx[jl], k-chunk g*8 -> lanes {j,j+16,j+32,j+48} cover one 64B line (16 lines
// per instr, fully used). A = pred row broadcast. Partial (m,s) combined in LDS.
__global__ __launch_bounds__(256) void loss_mfma(
    const ushort* __restrict__ embB, const ushort* __restrict__ predB,
    const int* __restrict__ neg_perm, float* __restrict__ row_loss) {
  const int tid = threadIdx.x;
  const int lane = tid & 63, wv = tid >> 6;
  const int n = blockIdx.x * 2 + (wv >> 1);   // 2 rows per block
  const int half = wv & 1;
  const int jl = lane & 15, g = lane >> 4;
  const int base = n * K_POS;
  __shared__ float smax[4], ssum[4], spos[4];

  // A fragment: predB row n (broadcast across the 16 M-rows)
  bf16x8 a[8];
  {
    const short* ap = (const short*)predB + (size_t)n * HID + g * 8;
#pragma unroll
    for (int kk = 0; kk < 8; ++kk) a[kk] = *(const bf16x8*)(ap + kk * 32);
  }

  // positive logit (half==0 wave only)
  float posv = 0.f;
  if (half == 0) {
    const ushort4 h = *(const ushort4*)(embB + ((size_t)n * K_POS + K_POS - 1) * HID + lane * 4);
    const ushort4 p = *(const ushort4*)(predB + (size_t)n * HID + lane * 4);
    float s = bf2f(h.x) * bf2f(p.x) + bf2f(h.y) * bf2f(p.y) +
              bf2f(h.z) * bf2f(p.z) + bf2f(h.w) * bf2f(p.w);
    s += __shfl_xor(s, 1);  s += __shfl_xor(s, 2);  s += __shfl_xor(s, 4);
    s += __shfl_xor(s, 8);  s += __shfl_xor(s, 16); s += __shfl_xor(s, 32);
    posv = s;
  }

  // hoist all 8 tile indices (independent loads, issued up front)
  const int* nb = neg_perm + (size_t)n * M_NEG + half * 128;
  int idx[8];
#pragma unroll
  for (int jt = 0; jt < 8; ++jt) {
    const int j = nb[jt * 16 + jl];
    idx[jt] = j + (j >= base ? K_POS : 0);
  }

  float m0 = -INFINITY, s0 = 0.f, m1 = -INFINITY, s1 = 0.f;
#pragma unroll
  for (int t = 0; t < 8; t += 2) {
    const short* bp0 = (const short*)embB + (size_t)idx[t] * HID + g * 8;
    const short* bp1 = (const short*)embB + (size_t)idx[t + 1] * HID + g * 8;
    f32x4 acc0 = {0.f, 0.f, 0.f, 0.f}, acc1 = {0.f, 0.f, 0.f, 0.f};
#pragma unroll
    for (int kk = 0; kk < 8; ++kk) {
      const bf16x8 b0 = *(const bf16x8*)(bp0 + kk * 32);
      acc0 = __builtin_amdgcn_mfma_f32_16x16x32_bf16(a[kk], b0, acc0, 0, 0, 0);
    }
#pragma unroll
    for (int kk = 0; kk < 8; ++kk) {
      const bf16x8 b1 = *(const bf16x8*)(bp1 + kk * 32);
      acc1 = __builtin_amdgcn_mfma_f32_16x16x32_bf16(a[kk], b1, acc1, 0, 0, 0);
    }
    const float v0 = acc0[0], v1 = acc1[0];
    { const float mn = fmaxf(m0, v0); s0 = s0 * __expf(m0 - mn) + __expf(v0 - mn); m0 = mn; }
    { const float mn = fmaxf(m1, v1); s1 = s1 * __expf(m1 - mn) + __expf(v1 - mn); m1 = mn; }
  }

  // merge chains, then wave reduce (each negative counted by 4 lane-groups -> /4)
  float m = fmaxf(m0, m1);
  float s = s0 * __expf(m0 - m) + s1 * __expf(m1 - m);

  float gm = m;
  gm = fmaxf(gm, __shfl_xor(gm, 1));  gm = fmaxf(gm, __shfl_xor(gm, 2));
  gm = fmaxf(gm, __shfl_xor(gm, 4));  gm = fmaxf(gm, __shfl_xor(gm, 8));
  gm = fmaxf(gm, __shfl_xor(gm, 16)); gm = fmaxf(gm, __shfl_xor(gm, 32));
  float sr = s * __expf(m - gm);
  sr += __shfl_xor(sr, 1);  sr += __shfl_xor(sr, 2);  sr += __shfl_xor(sr, 4);
  sr += __shfl_xor(sr, 8);  sr += __shfl_xor(sr, 16); sr += __shfl_xor(sr, 32);
  sr *= 0.25f;

  if (lane == 0) { smax[wv] = gm; ssum[wv] = sr; spos[wv] = posv; }
  __syncthreads();

  if (half == 0 && lane == 0) {
    const float ma = smax[wv], mb = smax[wv + 1];
    const float sa = ssum[wv], sb = ssum[wv + 1];
    const float pv = spos[wv];
    const float mm = fmaxf(fmaxf(ma, mb), pv);
    const float tot = sa * __expf(ma - mm) + sb * __expf(mb - mm) + __expf(pv - mm);
    row_loss[n] = __logf(tot) + mm - pv;
  }
}

// ---------------- Kernel 3: deterministic mean ----------------
__global__ __launch_bounds__(256) void reduce_mean(
    const float* __restrict__ row_loss, float* __restrict__ out) {
  const int tid = threadIdx.x;
  const int lane = tid & 63, wv = tid >> 6;
  float s = 0.f;
  for (int i = tid; i < N_GROUPS; i += 256) s += row_loss[i];
  s += __shfl_xor(s, 1);  s += __shfl_xor(s, 2);  s += __shfl_xor(s, 4);
  s += __shfl_xor(s, 8);  s += __shfl_xor(s, 16); s += __shfl_xor(s, 32);
  __shared__ float red[4];
  if (lane == 0) red[wv] = s;
  __syncthreads();
  if (tid == 0) out[0] = (red[0] + red[1] + red[2] + red[3]) * (1.0f / N_GROUPS);
}

extern "C" void kernel_launch(void* const* d_in, const int* in_sizes, int n_in,
                              void* d_out, int out_size, void* d_ws, size_t ws_size,
                              hipStream_t stream) {
  const float* emb = (const float*)d_in[0];
  const float* W = (const float*)d_in[1];
  const float* b = (const float*)d_in[2];
  const int* neg_perm = (const int*)d_in[4];
  float* out = (float*)d_out;

  ushort* embB = (ushort*)d_ws;                              // 8.4 MB
  ushort* WB = embB + (size_t)N_EMB * HID;                   // 0.4 MB
  ushort* predB = WB + (size_t)KDIM * HID;                   // 2.1 MB
  float* row_loss = (float*)(predB + (size_t)N_GROUPS * HID);

  const int n4 = N4_EMB + N4_W;
  to_bf16<<<(n4 + 255) / 256, 256, 0, stream>>>(emb, W, embB, WB);
  gemm_mfma<<<dim3(N_GROUPS / 64, HID / 64), 256, 0, stream>>>(embB, WB, b, predB);
  loss_mfma<<<N_GROUPS / 2, 256, 0, stream>>>(embB, predB, neg_perm, row_loss);
  reduce_mean<<<1, 256, 0, stream>>>(row_loss, out);
}

// Round 8
// 83.447 us; speedup vs baseline: 2.3328x; 1.1375x over previous
//
#include <hip/hip_runtime.h>

#define N_GROUPS 4096
#define K_POS 4
#define HID 256
#define M_NEG 256
#define KDIM 768  // (K_POS-1)*HID
#define N_EMB (N_GROUPS * K_POS)

typedef __attribute__((ext_vector_type(8))) short bf16x8;
typedef __attribute__((ext_vector_type(4))) float f32x4;
typedef __attribute__((ext_vector_type(4))) int i32x4;

#define QSCALE 32.0f
#define QDESCALE (1.0f / (QSCALE * QSCALE))

__device__ inline ushort f2bf(float f) {
  uint x = __float_as_uint(f);
  return (ushort)((x + 0x7fffu + ((x >> 16) & 1u)) >> 16);
}
__device__ inline float bf2f(ushort u) { return __uint_as_float(((uint)u) << 16); }

__device__ inline int q8(float x) {
  int q = __float2int_rn(x * QSCALE);
  return max(-127, min(127, q));
}
__device__ inline int pack4(float a, float b, float c, float d) {
  return (q8(a) & 0xff) | ((q8(b) & 0xff) << 8) | ((q8(c) & 0xff) << 16) | ((q8(d) & 0xff) << 24);
}

// ---------------- Kernel 0: emb fp32 -> i8 (embQ); W fp32 -> bf16 (WB) ----------------
#define N4_EMB (N_EMB * HID / 4)   // 1048576
#define N4_W   (KDIM * HID / 4)    // 49152
__global__ __launch_bounds__(256) void convert_in(
    const float* __restrict__ emb, const float* __restrict__ W,
    int* __restrict__ embQ, ushort* __restrict__ WB) {
  const int i = blockIdx.x * 256 + threadIdx.x;
  if (i < N4_EMB) {
    const float4 v = ((const float4*)emb)[i];
    embQ[i] = pack4(v.x, v.y, v.z, v.w);
  } else if (i < N4_EMB + N4_W) {
    const int j = i - N4_EMB;
    const float4 v = ((const float4*)W)[j];
    ushort4 o = {f2bf(v.x), f2bf(v.y), f2bf(v.z), f2bf(v.w)};
    ((ushort4*)WB)[j] = o;
  }
}

// ---------------- Kernel 1: predicts = hist_x @ W^T + b (MFMA, fp32 A converted) -----
__global__ __launch_bounds__(256) void gemm_mfma(
    const float* __restrict__ emb, const ushort* __restrict__ WB,
    const float* __restrict__ bias, ushort* __restrict__ predB) {
  const int wv = threadIdx.x >> 6, l = threadIdx.x & 63;
  const int mt = blockIdx.x * 4 + wv;
  const int bn = blockIdx.y * 64;
  const int r = l & 15, g = l >> 4;

  const float* A = emb + (size_t)(mt * 16 + r) * (K_POS * HID) + g * 8;
  f32x4 acc[4] = {{0,0,0,0},{0,0,0,0},{0,0,0,0},{0,0,0,0}};
  for (int k0 = 0; k0 < KDIM; k0 += 32) {
    const float4 a0 = *(const float4*)(A + k0);
    const float4 a1 = *(const float4*)(A + k0 + 4);
    bf16x8 a;
    a[0] = (short)f2bf(a0.x); a[1] = (short)f2bf(a0.y);
    a[2] = (short)f2bf(a0.z); a[3] = (short)f2bf(a0.w);
    a[4] = (short)f2bf(a1.x); a[5] = (short)f2bf(a1.y);
    a[6] = (short)f2bf(a1.z); a[7] = (short)f2bf(a1.w);
#pragma unroll
    for (int j = 0; j < 4; ++j) {
      const bf16x8 b = *(const bf16x8*)((const short*)WB + (size_t)(bn + j * 16 + r) * KDIM + g * 8 + k0);
      acc[j] = __builtin_amdgcn_mfma_f32_16x16x32_bf16(a, b, acc[j], 0, 0, 0);
    }
  }
  // C/D: col = lane&15, row = (lane>>4)*4 + i
#pragma unroll
  for (int j = 0; j < 4; ++j) {
    const int col = bn + j * 16 + r;
    const float bb = bias[col];
#pragma unroll
    for (int i = 0; i < 4; ++i)
      predB[(size_t)(mt * 16 + g * 4 + i) * HID + col] = f2bf(acc[j][i] + bb);
  }
}

// ---------------- Kernel 1b: quantize pred to i8 ----------------
__global__ __launch_bounds__(256) void pred_quant(
    const ushort* __restrict__ predB, int* __restrict__ predQ) {
  const int i = blockIdx.x * 256 + threadIdx.x;  // over 1048576/4 groups
  const ushort4 v = ((const ushort4*)predB)[i];
  predQ[i] = pack4(bf2f(v.x), bf2f(v.y), bf2f(v.z), bf2f(v.w));
}

// ---------------- Kernel 2: negative logits via i8 MFMA, 2 waves per row ------------
// Wave owns half a row (128 negs = 8 tiles of 16). Per tile: 4x mfma_i32_16x16x64_i8.
// B-fragment lane l: row idx[l&15], bytes [kk*64 + (l>>4)*16, +16) of the 256B row
// -> one dwordx4 per lane, lanes {c,c+16,c+32,c+48} cover one 64B line.
// A = predQ row with the SAME (g,byte)->k packing => k-permutation-invariant.
__global__ __launch_bounds__(256) void loss_mfma(
    const float* __restrict__ emb, const int* __restrict__ embQ,
    const ushort* __restrict__ predB, const int* __restrict__ predQ,
    const int* __restrict__ neg_perm, float* __restrict__ row_loss) {
  const int tid = threadIdx.x;
  const int lane = tid & 63, wv = tid >> 6;
  const int n = blockIdx.x * 2 + (wv >> 1);   // 2 rows per block
  const int half = wv & 1;
  const int jl = lane & 15, g = lane >> 4;
  const int base = n * K_POS;
  __shared__ float smax[4], ssum[4], spos[4];

  // A fragments: predQ row n, 4 K-slices of 16 bytes at (kk*64 + g*16) bytes
  i32x4 aQ[4];
  {
    const int* ap = predQ + (size_t)n * 64 + g * 4;
#pragma unroll
    for (int kk = 0; kk < 4; ++kk) aQ[kk] = *(const i32x4*)(ap + kk * 16);
  }

  // positive logit (half==0 wave only): fp32 emb x bf16 pred
  float posv = 0.f;
  if (half == 0) {
    const float4 h = *(const float4*)(emb + ((size_t)n * K_POS + K_POS - 1) * HID + lane * 4);
    const ushort4 p = *(const ushort4*)(predB + (size_t)n * HID + lane * 4);
    float s = h.x * bf2f(p.x) + h.y * bf2f(p.y) + h.z * bf2f(p.z) + h.w * bf2f(p.w);
    s += __shfl_xor(s, 1);  s += __shfl_xor(s, 2);  s += __shfl_xor(s, 4);
    s += __shfl_xor(s, 8);  s += __shfl_xor(s, 16); s += __shfl_xor(s, 32);
    posv = s;
  }

  // hoist all 8 tile indices
  const int* nb = neg_perm + (size_t)n * M_NEG + half * 128;
  int idx[8];
#pragma unroll
  for (int jt = 0; jt < 8; ++jt) {
    const int j = nb[jt * 16 + jl];
    idx[jt] = j + (j >= base ? K_POS : 0);
  }

  float m0 = -INFINITY, s0 = 0.f, m1 = -INFINITY, s1 = 0.f;
#pragma unroll
  for (int t = 0; t < 8; t += 2) {
    const int* bp0 = embQ + (size_t)idx[t] * 64 + g * 4;
    const int* bp1 = embQ + (size_t)idx[t + 1] * 64 + g * 4;
    i32x4 acc0 = {0, 0, 0, 0}, acc1 = {0, 0, 0, 0};
#pragma unroll
    for (int kk = 0; kk < 4; ++kk) {
      const i32x4 b0 = *(const i32x4*)(bp0 + kk * 16);
      acc0 = __builtin_amdgcn_mfma_i32_16x16x64_i8(aQ[kk], b0, acc0, 0, 0, 0);
    }
#pragma unroll
    for (int kk = 0; kk < 4; ++kk) {
      const i32x4 b1 = *(const i32x4*)(bp1 + kk * 16);
      acc1 = __builtin_amdgcn_mfma_i32_16x16x64_i8(aQ[kk], b1, acc1, 0, 0, 0);
    }
    const float v0 = (float)acc0[0] * QDESCALE;
    const float v1 = (float)acc1[0] * QDESCALE;
    { const float mn = fmaxf(m0, v0); s0 = s0 * __expf(m0 - mn) + __expf(v0 - mn); m0 = mn; }
    { const float mn = fmaxf(m1, v1); s1 = s1 * __expf(m1 - mn) + __expf(v1 - mn); m1 = mn; }
  }

  // merge chains, then wave reduce (each negative counted by 4 lane-groups -> /4)
  float m = fmaxf(m0, m1);
  float s = s0 * __expf(m0 - m) + s1 * __expf(m1 - m);

  float gm = m;
  gm = fmaxf(gm, __shfl_xor(gm, 1));  gm = fmaxf(gm, __shfl_xor(gm, 2));
  gm = fmaxf(gm, __shfl_xor(gm, 4));  gm = fmaxf(gm, __shfl_xor(gm, 8));
  gm = fmaxf(gm, __shfl_xor(gm, 16)); gm = fmaxf(gm, __shfl_xor(gm, 32));
  float sr = s * __expf(m - gm);
  sr += __shfl_xor(sr, 1);  sr += __shfl_xor(sr, 2);  sr += __shfl_xor(sr, 4);
  sr += __shfl_xor(sr, 8);  sr += __shfl_xor(sr, 16); sr += __shfl_xor(sr, 32);
  sr *= 0.25f;

  if (lane == 0) { smax[wv] = gm; ssum[wv] = sr; spos[wv] = posv; }
  __syncthreads();

  if (half == 0 && lane == 0) {
    const float ma = smax[wv], mb = smax[wv + 1];
    const float sa = ssum[wv], sb = ssum[wv + 1];
    const float pv = spos[wv];
    const float mm = fmaxf(fmaxf(ma, mb), pv);
    const float tot = sa * __expf(ma - mm) + sb * __expf(mb - mm) + __expf(pv - mm);
    row_loss[n] = __logf(tot) + mm - pv;
  }
}

// ---------------- Kernel 3: deterministic mean ----------------
__global__ __launch_bounds__(256) void reduce_mean(
    const float* __restrict__ row_loss, float* __restrict__ out) {
  const int tid = threadIdx.x;
  const int lane = tid & 63, wv = tid >> 6;
  float s = 0.f;
  for (int i = tid; i < N_GROUPS; i += 256) s += row_loss[i];
  s += __shfl_xor(s, 1);  s += __shfl_xor(s, 2);  s += __shfl_xor(s, 4);
  s += __shfl_xor(s, 8);  s += __shfl_xor(s, 16); s += __shfl_xor(s, 32);
  __shared__ float red[4];
  if (lane == 0) red[wv] = s;
  __syncthreads();
  if (tid == 0) out[0] = (red[0] + red[1] + red[2] + red[3]) * (1.0f / N_GROUPS);
}

extern "C" void kernel_launch(void* const* d_in, const int* in_sizes, int n_in,
                              void* d_out, int out_size, void* d_ws, size_t ws_size,
                              hipStream_t stream) {
  const float* emb = (const float*)d_in[0];
  const float* W = (const float*)d_in[1];
  const float* b = (const float*)d_in[2];
  const int* neg_perm = (const int*)d_in[4];
  float* out = (float*)d_out;

  int* embQ = (int*)d_ws;                                    // 4.2 MB (i8 packed)
  ushort* WB = (ushort*)(embQ + (size_t)N_EMB * HID / 4);    // 0.4 MB
  ushort* predB = WB + (size_t)KDIM * HID;                   // 2.1 MB
  int* predQ = (int*)(predB + (size_t)N_GROUPS * HID);       // 1.05 MB
  float* row_loss = (float*)(predQ + (size_t)N_GROUPS * HID / 4);

  const int n4 = N4_EMB + N4_W;
  convert_in<<<(n4 + 255) / 256, 256, 0, stream>>>(emb, W, embQ, WB);
  gemm_mfma<<<dim3(N_GROUPS / 64, HID / 64), 256, 0, stream>>>(emb, WB, b, predB);
  pred_quant<<<N_GROUPS * HID / 4 / 256, 256, 0, stream>>>(predB, predQ);
  loss_mfma<<<N_GROUPS / 2, 256, 0, stream>>>(emb, embQ, predB, predQ, neg_perm, row_loss);
  reduce_mean<<<1, 256, 0, stream>>>(row_loss, out);
}

// Round 9
// 74.860 us; speedup vs baseline: 2.6004x; 1.1147x over previous
//
#include <hip/hip_runtime.h>

#define N_GROUPS 4096
#define K_POS 4
#define HID 256
#define M_NEG 256
#define KDIM 768  // (K_POS-1)*HID
#define N_EMB (N_GROUPS * K_POS)

typedef __attribute__((ext_vector_type(8))) short bf16x8;
typedef __attribute__((ext_vector_type(4))) float f32x4;
typedef __attribute__((ext_vector_type(4))) int i32x4;

#define QSCALE 32.0f
#define QDESCALE (1.0f / (QSCALE * QSCALE))

__device__ inline ushort f2bf(float f) {
  uint x = __float_as_uint(f);
  return (ushort)((x + 0x7fffu + ((x >> 16) & 1u)) >> 16);
}
__device__ inline float bf2f(ushort u) { return __uint_as_float(((uint)u) << 16); }

__device__ inline int q8(float x) {
  int q = __float2int_rn(x * QSCALE);
  return max(-127, min(127, q));
}
__device__ inline int pack4(float a, float b, float c, float d) {
  return (q8(a) & 0xff) | ((q8(b) & 0xff) << 8) | ((q8(c) & 0xff) << 16) | ((q8(d) & 0xff) << 24);
}

// ---------------- Kernel 0: emb fp32 -> bf16 + i8; W fp32 -> bf16 ----------------
#define N4_EMB (N_EMB * HID / 4)   // 1048576
#define N4_W   (KDIM * HID / 4)    // 49152
__global__ __launch_bounds__(256) void convert_in(
    const float* __restrict__ emb, const float* __restrict__ W,
    ushort* __restrict__ embB, int* __restrict__ embQ, ushort* __restrict__ WB) {
  const int i = blockIdx.x * 256 + threadIdx.x;
  if (i < N4_EMB) {
    const float4 v = ((const float4*)emb)[i];
    ushort4 o = {f2bf(v.x), f2bf(v.y), f2bf(v.z), f2bf(v.w)};
    ((ushort4*)embB)[i] = o;
    embQ[i] = pack4(v.x, v.y, v.z, v.w);
  } else if (i < N4_EMB + N4_W) {
    const int j = i - N4_EMB;
    const float4 v = ((const float4*)W)[j];
    ushort4 o = {f2bf(v.x), f2bf(v.y), f2bf(v.z), f2bf(v.w)};
    ((ushort4*)WB)[j] = o;
  }
}

// ---------------- Kernel 1: predicts = hist_x @ W^T + b (MFMA bf16, f32 out) -------
// grid (64,16) = 1024 blocks, 4 waves each; wave owns one 16x16 output tile.
// Per k-step: one 16B A-load + one 16B B-load (16 fully-used lines each) + 1 MFMA.
__global__ __launch_bounds__(256) void gemm_mfma(
    const ushort* __restrict__ embB, const ushort* __restrict__ WB,
    const float* __restrict__ bias, float* __restrict__ pred) {
  const int wv = threadIdx.x >> 6, l = threadIdx.x & 63;
  const int mt = blockIdx.x * 4 + wv;   // 0..255 row-tiles
  const int nt = blockIdx.y;            // 0..15 col-tiles
  const int r = l & 15, g = l >> 4;

  const short* A = (const short*)embB + (size_t)(mt * 16 + r) * (K_POS * HID) + g * 8;
  const short* B = (const short*)WB + (size_t)(nt * 16 + r) * KDIM + g * 8;

  f32x4 acc = {0.f, 0.f, 0.f, 0.f};
#pragma unroll
  for (int k0 = 0; k0 < KDIM; k0 += 32) {
    const bf16x8 a = *(const bf16x8*)(A + k0);
    const bf16x8 b = *(const bf16x8*)(B + k0);
    acc = __builtin_amdgcn_mfma_f32_16x16x32_bf16(a, b, acc, 0, 0, 0);
  }
  // C/D: col = lane&15, row = (lane>>4)*4 + i
  const int col = nt * 16 + r;
  const float bb = bias[col];
#pragma unroll
  for (int i = 0; i < 4; ++i)
    pred[(size_t)(mt * 16 + g * 4 + i) * HID + col] = acc[i] + bb;
}

// ---------------- Kernel 2: negative logits via i8 MFMA, 2 waves per row ------------
// Wave owns half a row (128 negs = 8 tiles of 16). Per tile: 4x mfma_i32_16x16x64_i8.
// B-fragment lane l: row idx[l&15], bytes [kk*64 + (l>>4)*16, +16) -> one dwordx4
// per lane; lanes {c,c+16,c+32,c+48} cover one 64B line. A = pred row quantized
// in-register with the SAME (g,byte)->k packing => k-permutation-invariant.
__global__ __launch_bounds__(256) void loss_mfma(
    const float* __restrict__ emb, const int* __restrict__ embQ,
    const float* __restrict__ pred, const int* __restrict__ neg_perm,
    float* __restrict__ row_loss) {
  const int tid = threadIdx.x;
  const int lane = tid & 63, wv = tid >> 6;
  const int n = blockIdx.x * 2 + (wv >> 1);   // 2 rows per block
  const int half = wv & 1;
  const int jl = lane & 15, g = lane >> 4;
  const int base = n * K_POS;
  __shared__ float smax[4], ssum[4], spos[4];

  // A fragments: quantize pred row n in-register (elems kk*64 + g*16 .. +15)
  const float* pr = pred + (size_t)n * HID;
  i32x4 aQ[4];
#pragma unroll
  for (int kk = 0; kk < 4; ++kk) {
    const float4 f0 = *(const float4*)(pr + kk * 64 + g * 16);
    const float4 f1 = *(const float4*)(pr + kk * 64 + g * 16 + 4);
    const float4 f2 = *(const float4*)(pr + kk * 64 + g * 16 + 8);
    const float4 f3 = *(const float4*)(pr + kk * 64 + g * 16 + 12);
    aQ[kk][0] = pack4(f0.x, f0.y, f0.z, f0.w);
    aQ[kk][1] = pack4(f1.x, f1.y, f1.z, f1.w);
    aQ[kk][2] = pack4(f2.x, f2.y, f2.z, f2.w);
    aQ[kk][3] = pack4(f3.x, f3.y, f3.z, f3.w);
  }

  // positive logit (half==0 wave only): fp32 x fp32
  float posv = 0.f;
  if (half == 0) {
    const float4 h = *(const float4*)(emb + ((size_t)n * K_POS + K_POS - 1) * HID + lane * 4);
    const float4 p = *(const float4*)(pr + lane * 4);
    float s = h.x * p.x + h.y * p.y + h.z * p.z + h.w * p.w;
    s += __shfl_xor(s, 1);  s += __shfl_xor(s, 2);  s += __shfl_xor(s, 4);
    s += __shfl_xor(s, 8);  s += __shfl_xor(s, 16); s += __shfl_xor(s, 32);
    posv = s;
  }

  // hoist all 8 tile indices
  const int* nb = neg_perm + (size_t)n * M_NEG + half * 128;
  int idx[8];
#pragma unroll
  for (int jt = 0; jt < 8; ++jt) {
    const int j = nb[jt * 16 + jl];
    idx[jt] = j + (j >= base ? K_POS : 0);
  }

  float m0 = -INFINITY, s0 = 0.f, m1 = -INFINITY, s1 = 0.f;
#pragma unroll
  for (int t = 0; t < 8; t += 2) {
    const int* bp0 = embQ + (size_t)idx[t] * 64 + g * 4;
    const int* bp1 = embQ + (size_t)idx[t + 1] * 64 + g * 4;
    i32x4 acc0 = {0, 0, 0, 0}, acc1 = {0, 0, 0, 0};
#pragma unroll
    for (int kk = 0; kk < 4; ++kk) {
      const i32x4 b0 = *(const i32x4*)(bp0 + kk * 16);
      acc0 = __builtin_amdgcn_mfma_i32_16x16x64_i8(aQ[kk], b0, acc0, 0, 0, 0);
    }
#pragma unroll
    for (int kk = 0; kk < 4; ++kk) {
      const i32x4 b1 = *(const i32x4*)(bp1 + kk * 16);
      acc1 = __builtin_amdgcn_mfma_i32_16x16x64_i8(aQ[kk], b1, acc1, 0, 0, 0);
    }
    const float v0 = (float)acc0[0] * QDESCALE;
    const float v1 = (float)acc1[0] * QDESCALE;
    { const float mn = fmaxf(m0, v0); s0 = s0 * __expf(m0 - mn) + __expf(v0 - mn); m0 = mn; }
    { const float mn = fmaxf(m1, v1); s1 = s1 * __expf(m1 - mn) + __expf(v1 - mn); m1 = mn; }
  }

  // merge chains, then wave reduce (each negative counted by 4 lane-groups -> /4)
  float m = fmaxf(m0, m1);
  float s = s0 * __expf(m0 - m) + s1 * __expf(m1 - m);

  float gm = m;
  gm = fmaxf(gm, __shfl_xor(gm, 1));  gm = fmaxf(gm, __shfl_xor(gm, 2));
  gm = fmaxf(gm, __shfl_xor(gm, 4));  gm = fmaxf(gm, __shfl_xor(gm, 8));
  gm = fmaxf(gm, __shfl_xor(gm, 16)); gm = fmaxf(gm, __shfl_xor(gm, 32));
  float sr = s * __expf(m - gm);
  sr += __shfl_xor(sr, 1);  sr += __shfl_xor(sr, 2);  sr += __shfl_xor(sr, 4);
  sr += __shfl_xor(sr, 8);  sr += __shfl_xor(sr, 16); sr += __shfl_xor(sr, 32);
  sr *= 0.25f;

  if (lane == 0) { smax[wv] = gm; ssum[wv] = sr; spos[wv] = posv; }
  __syncthreads();

  if (half == 0 && lane == 0) {
    const float ma = smax[wv], mb = smax[wv + 1];
    const float sa = ssum[wv], sb = ssum[wv + 1];
    const float pv = spos[wv];
    const float mm = fmaxf(fmaxf(ma, mb), pv);
    const float tot = sa * __expf(ma - mm) + sb * __expf(mb - mm) + __expf(pv - mm);
    row_loss[n] = __logf(tot) + mm - pv;
  }
}

// ---------------- Kernel 3: deterministic mean ----------------
__global__ __launch_bounds__(256) void reduce_mean(
    const float* __restrict__ row_loss, float* __restrict__ out) {
  const int tid = threadIdx.x;
  const int lane = tid & 63, wv = tid >> 6;
  float s = 0.f;
  for (int i = tid; i < N_GROUPS; i += 256) s += row_loss[i];
  s += __shfl_xor(s, 1);  s += __shfl_xor(s, 2);  s += __shfl_xor(s, 4);
  s += __shfl_xor(s, 8);  s += __shfl_xor(s, 16); s += __shfl_xor(s, 32);
  __shared__ float red[4];
  if (lane == 0) red[wv] = s;
  __syncthreads();
  if (tid == 0) out[0] = (red[0] + red[1] + red[2] + red[3]) * (1.0f / N_GROUPS);
}

extern "C" void kernel_launch(void* const* d_in, const int* in_sizes, int n_in,
                              void* d_out, int out_size, void* d_ws, size_t ws_size,
                              hipStream_t stream) {
  const float* emb = (const float*)d_in[0];
  const float* W = (const float*)d_in[1];
  const float* b = (const float*)d_in[2];
  const int* neg_perm = (const int*)d_in[4];
  float* out = (float*)d_out;

  ushort* embB = (ushort*)d_ws;                              // 8.4 MB
  int* embQ = (int*)(embB + (size_t)N_EMB * HID);            // 4.2 MB
  ushort* WB = (ushort*)(embQ + (size_t)N_EMB * HID / 4);    // 0.4 MB
  float* pred = (float*)(WB + (size_t)KDIM * HID);           // 4.2 MB
  float* row_loss = pred + (size_t)N_GROUPS * HID;           // 16 KB

  const int n4 = N4_EMB + N4_W;
  convert_in<<<(n4 + 255) / 256, 256, 0, stream>>>(emb, W, embB, embQ, WB);
  gemm_mfma<<<dim3(N_GROUPS / 64, HID / 16), 256, 0, stream>>>(embB, WB, b, pred);
  loss_mfma<<<N_GROUPS / 2, 256, 0, stream>>>(emb, embQ, pred, neg_perm, row_loss);
  reduce_mean<<<1, 256, 0, stream>>>(row_loss, out);
}

// Round 10
// 62.916 us; speedup vs baseline: 3.0941x; 1.1898x over previous
//
#include <hip/hip_runtime.h>

#define N_GROUPS 4096
#define K_POS 4
#define HID 256
#define M_NEG 256
#define KDIM 768  // (K_POS-1)*HID
#define N_EMB (N_GROUPS * K_POS)

typedef __attribute__((ext_vector_type(4))) float f32x4;
typedef __attribute__((ext_vector_type(4))) int i32x4;

#define QSCALE 32.0f            // emb & pred quant scale
#define WSCALE 512.0f           // W quant scale
#define QDESCALE (1.0f / (QSCALE * QSCALE))
#define GDESCALE (1.0f / (QSCALE * WSCALE))

__device__ inline ushort f2bf(float f) {
  uint x = __float_as_uint(f);
  return (ushort)((x + 0x7fffu + ((x >> 16) & 1u)) >> 16);
}
__device__ inline float bf2f(ushort u) { return __uint_as_float(((uint)u) << 16); }

__device__ inline int q8(float x, float scale) {
  int q = __float2int_rn(x * scale);
  return max(-127, min(127, q));
}
__device__ inline int pack4(float a, float b, float c, float d, float s) {
  return (q8(a, s) & 0xff) | ((q8(b, s) & 0xff) << 8) |
         ((q8(c, s) & 0xff) << 16) | ((q8(d, s) & 0xff) << 24);
}

// ---------------- Kernel 0: emb fp32 -> i8 (scale 32); W fp32 -> i8 (scale 512) -----
#define N4_EMB (N_EMB * HID / 4)   // 1048576
#define N4_W   (KDIM * HID / 4)    // 49152
__global__ __launch_bounds__(256) void convert_in(
    const float* __restrict__ emb, const float* __restrict__ W,
    int* __restrict__ embQ, int* __restrict__ WQ) {
  const int i = blockIdx.x * 256 + threadIdx.x;
  if (i < N4_EMB) {
    const float4 v = ((const float4*)emb)[i];
    embQ[i] = pack4(v.x, v.y, v.z, v.w, QSCALE);
  } else if (i < N4_EMB + N4_W) {
    const int j = i - N4_EMB;
    const float4 v = ((const float4*)W)[j];
    WQ[j] = pack4(v.x, v.y, v.z, v.w, WSCALE);
  }
}

// ---------------- Kernel 1: predicts = hist_x @ W^T + b (i8 MFMA, bf16 out) --------
// grid (64,16) = 1024 blocks, 4 waves; wave owns one 16x16 tile; 12 k-steps of 64.
// A row m: embQ ints [m*256 + kk*16 + g*4, +4). B row c: WQ ints [c*192 + kk*16 + g*4).
// Same (g,byte)->k packing on both sides => k-permutation-invariant.
__global__ __launch_bounds__(256) void gemm_i8(
    const int* __restrict__ embQ, const int* __restrict__ WQ,
    const float* __restrict__ bias, ushort* __restrict__ predB) {
  const int wv = threadIdx.x >> 6, l = threadIdx.x & 63;
  const int mt = blockIdx.x * 4 + wv;   // 0..255 row-tiles
  const int nt = blockIdx.y;            // 0..15 col-tiles
  const int r = l & 15, g = l >> 4;

  const int* A = embQ + (size_t)(mt * 16 + r) * (K_POS * HID / 4) + g * 4;
  const int* B = WQ + (size_t)(nt * 16 + r) * (KDIM / 4) + g * 4;

  i32x4 acc = {0, 0, 0, 0};
#pragma unroll
  for (int kk = 0; kk < 12; ++kk) {
    const i32x4 a = *(const i32x4*)(A + kk * 16);
    const i32x4 b = *(const i32x4*)(B + kk * 16);
    acc = __builtin_amdgcn_mfma_i32_16x16x64_i8(a, b, acc, 0, 0, 0);
  }
  // C/D: col = lane&15, row = (lane>>4)*4 + i
  const int col = nt * 16 + r;
  const float bb = bias[col];
#pragma unroll
  for (int i = 0; i < 4; ++i)
    predB[(size_t)(mt * 16 + g * 4 + i) * HID + col] =
        f2bf((float)acc[i] * GDESCALE + bb);
}

// ---------------- Kernel 2: negative logits via i8 MFMA, 2 waves per row ------------
// Wave owns half a row (128 negs = 8 tiles of 16). Per tile: 4x mfma_i32_16x16x64_i8.
// B-fragment lane l: row idx[l&15], bytes [kk*64 + (l>>4)*16, +16) -> one dwordx4
// per lane; lanes {c,c+16,c+32,c+48} cover one 64B line. A = pred row (bf16)
// quantized in-register with the SAME (g,byte)->k packing.
__global__ __launch_bounds__(256) void loss_mfma(
    const float* __restrict__ emb, const int* __restrict__ embQ,
    const ushort* __restrict__ predB, const int* __restrict__ neg_perm,
    float* __restrict__ row_loss) {
  const int tid = threadIdx.x;
  const int lane = tid & 63, wv = tid >> 6;
  const int n = blockIdx.x * 2 + (wv >> 1);   // 2 rows per block
  const int half = wv & 1;
  const int jl = lane & 15, g = lane >> 4;
  const int base = n * K_POS;
  __shared__ float smax[4], ssum[4], spos[4];

  // A fragments: quantize pred row n (bf16) in-register; elems [kk*64+g*16, +16)
  const ushort* pr = predB + (size_t)n * HID;
  i32x4 aQ[4];
#pragma unroll
  for (int kk = 0; kk < 4; ++kk) {
    const ushort4 u0 = *(const ushort4*)(pr + kk * 64 + g * 16);
    const ushort4 u1 = *(const ushort4*)(pr + kk * 64 + g * 16 + 4);
    const ushort4 u2 = *(const ushort4*)(pr + kk * 64 + g * 16 + 8);
    const ushort4 u3 = *(const ushort4*)(pr + kk * 64 + g * 16 + 12);
    aQ[kk][0] = pack4(bf2f(u0.x), bf2f(u0.y), bf2f(u0.z), bf2f(u0.w), QSCALE);
    aQ[kk][1] = pack4(bf2f(u1.x), bf2f(u1.y), bf2f(u1.z), bf2f(u1.w), QSCALE);
    aQ[kk][2] = pack4(bf2f(u2.x), bf2f(u2.y), bf2f(u2.z), bf2f(u2.w), QSCALE);
    aQ[kk][3] = pack4(bf2f(u3.x), bf2f(u3.y), bf2f(u3.z), bf2f(u3.w), QSCALE);
  }

  // positive logit (half==0 wave only): fp32 emb x bf16 pred
  float posv = 0.f;
  if (half == 0) {
    const float4 h = *(const float4*)(emb + ((size_t)n * K_POS + K_POS - 1) * HID + lane * 4);
    const ushort4 p = *(const ushort4*)(pr + lane * 4);
    float s = h.x * bf2f(p.x) + h.y * bf2f(p.y) + h.z * bf2f(p.z) + h.w * bf2f(p.w);
    s += __shfl_xor(s, 1);  s += __shfl_xor(s, 2);  s += __shfl_xor(s, 4);
    s += __shfl_xor(s, 8);  s += __shfl_xor(s, 16); s += __shfl_xor(s, 32);
    posv = s;
  }

  // hoist all 8 tile indices
  const int* nb = neg_perm + (size_t)n * M_NEG + half * 128;
  int idx[8];
#pragma unroll
  for (int jt = 0; jt < 8; ++jt) {
    const int j = nb[jt * 16 + jl];
    idx[jt] = j + (j >= base ? K_POS : 0);
  }

  float m0 = -INFINITY, s0 = 0.f, m1 = -INFINITY, s1 = 0.f;
#pragma unroll
  for (int t = 0; t < 8; t += 2) {
    const int* bp0 = embQ + (size_t)idx[t] * 64 + g * 4;
    const int* bp1 = embQ + (size_t)idx[t + 1] * 64 + g * 4;
    i32x4 acc0 = {0, 0, 0, 0}, acc1 = {0, 0, 0, 0};
#pragma unroll
    for (int kk = 0; kk < 4; ++kk) {
      const i32x4 b0 = *(const i32x4*)(bp0 + kk * 16);
      acc0 = __builtin_amdgcn_mfma_i32_16x16x64_i8(aQ[kk], b0, acc0, 0, 0, 0);
    }
#pragma unroll
    for (int kk = 0; kk < 4; ++kk) {
      const i32x4 b1 = *(const i32x4*)(bp1 + kk * 16);
      acc1 = __builtin_amdgcn_mfma_i32_16x16x64_i8(aQ[kk], b1, acc1, 0, 0, 0);
    }
    const float v0 = (float)acc0[0] * QDESCALE;
    const float v1 = (float)acc1[0] * QDESCALE;
    { const float mn = fmaxf(m0, v0); s0 = s0 * __expf(m0 - mn) + __expf(v0 - mn); m0 = mn; }
    { const float mn = fmaxf(m1, v1); s1 = s1 * __expf(m1 - mn) + __expf(v1 - mn); m1 = mn; }
  }

  // merge chains, then wave reduce (each negative counted by 4 lane-groups -> /4)
  float m = fmaxf(m0, m1);
  float s = s0 * __expf(m0 - m) + s1 * __expf(m1 - m);

  float gm = m;
  gm = fmaxf(gm, __shfl_xor(gm, 1));  gm = fmaxf(gm, __shfl_xor(gm, 2));
  gm = fmaxf(gm, __shfl_xor(gm, 4));  gm = fmaxf(gm, __shfl_xor(gm, 8));
  gm = fmaxf(gm, __shfl_xor(gm, 16)); gm = fmaxf(gm, __shfl_xor(gm, 32));
  float sr = s * __expf(m - gm);
  sr += __shfl_xor(sr, 1);  sr += __shfl_xor(sr, 2);  sr += __shfl_xor(sr, 4);
  sr += __shfl_xor(sr, 8);  sr += __shfl_xor(sr, 16); sr += __shfl_xor(sr, 32);
  sr *= 0.25f;

  if (lane == 0) { smax[wv] = gm; ssum[wv] = sr; spos[wv] = posv; }
  __syncthreads();

  if (half == 0 && lane == 0) {
    const float ma = smax[wv], mb = smax[wv + 1];
    const float sa = ssum[wv], sb = ssum[wv + 1];
    const float pv = spos[wv];
    const float mm = fmaxf(fmaxf(ma, mb), pv);
    const float tot = sa * __expf(ma - mm) + sb * __expf(mb - mm) + __expf(pv - mm);
    row_loss[n] = __logf(tot) + mm - pv;
  }
}

// ---------------- Kernel 3: deterministic mean ----------------
__global__ __launch_bounds__(256) void reduce_mean(
    const float* __restrict__ row_loss, float* __restrict__ out) {
  const int tid = threadIdx.x;
  const int lane = tid & 63, wv = tid >> 6;
  float s = 0.f;
  for (int i = tid; i < N_GROUPS; i += 256) s += row_loss[i];
  s += __shfl_xor(s, 1);  s += __shfl_xor(s, 2);  s += __shfl_xor(s, 4);
  s += __shfl_xor(s, 8);  s += __shfl_xor(s, 16); s += __shfl_xor(s, 32);
  __shared__ float red[4];
  if (lane == 0) red[wv] = s;
  __syncthreads();
  if (tid == 0) out[0] = (red[0] + red[1] + red[2] + red[3]) * (1.0f / N_GROUPS);
}

extern "C" void kernel_launch(void* const* d_in, const int* in_sizes, int n_in,
                              void* d_out, int out_size, void* d_ws, size_t ws_size,
                              hipStream_t stream) {
  const float* emb = (const float*)d_in[0];
  const float* W = (const float*)d_in[1];
  const float* b = (const float*)d_in[2];
  const int* neg_perm = (const int*)d_in[4];
  float* out = (float*)d_out;

  int* embQ = (int*)d_ws;                                    // 4.2 MB (i8 packed)
  int* WQ = embQ + (size_t)N_EMB * HID / 4;                  // 0.2 MB
  ushort* predB = (ushort*)(WQ + (size_t)KDIM * HID / 4);    // 2.1 MB (bf16)
  float* row_loss = (float*)(predB + (size_t)N_GROUPS * HID);

  const int n4 = N4_EMB + N4_W;
  convert_in<<<(n4 + 255) / 256, 256, 0, stream>>>(emb, W, embQ, WQ);
  gemm_i8<<<dim3(N_GROUPS / 64, HID / 16), 256, 0, stream>>>(embQ, WQ, b, predB);
  loss_mfma<<<N_GROUPS / 2, 256, 0, stream>>>(emb, embQ, predB, neg_perm, row_loss);
  reduce_mean<<<1, 256, 0, stream>>>(row_loss, out);
}

// Round 11
// 55.317 us; speedup vs baseline: 3.5191x; 1.1374x over previous
//
#include <hip/hip_runtime.h>

#define N_GROUPS 4096
#define K_POS 4
#define HID 256
#define M_NEG 256
#define KDIM 768  // (K_POS-1)*HID
#define N_EMB (N_GROUPS * K_POS)

typedef __attribute__((ext_vector_type(4))) float f32x4;
typedef __attribute__((ext_vector_type(4))) int i32x4;

#define QSCALE 32.0f            // emb & pred quant scale
#define WSCALE 512.0f           // W quant scale
#define QDESCALE (1.0f / (QSCALE * QSCALE))
#define GDESCALE (1.0f / (QSCALE * WSCALE))

__device__ inline int q8(float x, float scale) {
  int q = __float2int_rn(x * scale);
  return max(-127, min(127, q));
}
__device__ inline int pack4(float a, float b, float c, float d, float s) {
  return (q8(a, s) & 0xff) | ((q8(b, s) & 0xff) << 8) |
         ((q8(c, s) & 0xff) << 16) | ((q8(d, s) & 0xff) << 24);
}
// signed i8 lane extraction
__device__ inline int sb(int v, int k) { return (v << (24 - 8 * k)) >> 24; }

// ---------------- Kernel 0: emb fp32 -> i8 (scale 32); W fp32 -> i8 (scale 512) -----
#define N4_EMB (N_EMB * HID / 4)   // 1048576
#define N4_W   (KDIM * HID / 4)    // 49152
__global__ __launch_bounds__(256) void convert_in(
    const float* __restrict__ emb, const float* __restrict__ W,
    int* __restrict__ embQ, int* __restrict__ WQ) {
  const int i = blockIdx.x * 256 + threadIdx.x;
  if (i < N4_EMB) {
    const float4 v = ((const float4*)emb)[i];
    embQ[i] = pack4(v.x, v.y, v.z, v.w, QSCALE);
  } else if (i < N4_EMB + N4_W) {
    const int j = i - N4_EMB;
    const float4 v = ((const float4*)W)[j];
    WQ[j] = pack4(v.x, v.y, v.z, v.w, WSCALE);
  }
}

// ---------------- Kernel 1: predicts = hist_x @ W^T + b -> i8 predQ directly --------
// grid (64,4), 4 waves. Wave owns 16 rows (mt), iterates 4 col-tiles with its 12
// A-fragments held in VGPRs (A L2 traffic /4). Epilogue: descale+bias, transpose
// 16x16 f32 tile through per-wave LDS, quantize to i8, write predQ row-major.
__global__ __launch_bounds__(256) void gemm_i8(
    const int* __restrict__ embQ, const int* __restrict__ WQ,
    const float* __restrict__ bias, int* __restrict__ predQ) {
  const int wv = threadIdx.x >> 6, l = threadIdx.x & 63;
  const int mt = blockIdx.x * 4 + wv;   // 0..255 row-tile
  const int nt0 = blockIdx.y * 4;       // first of 4 col-tiles
  const int r = l & 15, g = l >> 4;
  __shared__ float sT[4][16 * 16];      // per-wave transpose buffer

  const int* A = embQ + (size_t)(mt * 16 + r) * (K_POS * HID / 4) + g * 4;
  i32x4 a[12];
#pragma unroll
  for (int kk = 0; kk < 12; ++kk) a[kk] = *(const i32x4*)(A + kk * 16);

#pragma unroll
  for (int j = 0; j < 4; ++j) {
    const int nt = nt0 + j;
    const int* B = WQ + (size_t)(nt * 16 + r) * (KDIM / 4) + g * 4;
    i32x4 acc = {0, 0, 0, 0};
#pragma unroll
    for (int kk = 0; kk < 12; ++kk) {
      const i32x4 b = *(const i32x4*)(B + kk * 16);
      acc = __builtin_amdgcn_mfma_i32_16x16x64_i8(a[kk], b, acc, 0, 0, 0);
    }
    // C/D: col = r, row = g*4+i.  Stage f32 into [row][col], then repack by rows.
    const float bb = bias[nt * 16 + r];
#pragma unroll
    for (int i = 0; i < 4; ++i)
      sT[wv][(g * 4 + i) * 16 + r] = (float)acc[i] * GDESCALE + bb;
    // wave-synchronous LDS (no cross-wave sharing): compiler inserts lgkmcnt
    const int row = l >> 2, cb = l & 3;  // lane packs 4 consecutive cols of one row
    const float4 v = *(const float4*)&sT[wv][row * 16 + cb * 4];
    predQ[(size_t)(mt * 16 + row) * (HID / 4) + nt * 4 + cb] =
        pack4(v.x, v.y, v.z, v.w, QSCALE);
  }
}

// ---------------- Kernel 2: negative logits via i8 MFMA, 2 waves per row ------------
// Wave owns half a row (128 negs = 8 tiles of 16). Per tile: 4x mfma_i32_16x16x64_i8.
// B-fragment lane l: row idx[l&15], bytes [kk*64 + (l>>4)*16, +16) -> one dwordx4
// per lane; lanes {c,c+16,c+32,c+48} cover one 64B line. A = predQ row (i8, same
// (g,byte)->k packing as embQ => k-permutation-invariant).
__global__ __launch_bounds__(256) void loss_mfma(
    const int* __restrict__ embQ, const int* __restrict__ predQ,
    const int* __restrict__ neg_perm, float* __restrict__ row_loss) {
  const int tid = threadIdx.x;
  const int lane = tid & 63, wv = tid >> 6;
  const int n = blockIdx.x * 2 + (wv >> 1);   // 2 rows per block
  const int half = wv & 1;
  const int jl = lane & 15, g = lane >> 4;
  const int base = n * K_POS;
  __shared__ float smax[4], ssum[4], spos[4];

  // A fragments: predQ row n, ints [kk*16 + g*4, +4)
  const int* pq = predQ + (size_t)n * 64;
  i32x4 aQ[4];
#pragma unroll
  for (int kk = 0; kk < 4; ++kk) aQ[kk] = *(const i32x4*)(pq + kk * 16 + g * 4);

  // positive logit (half==0 wave only): i8 x i8 via VALU (1 int = 4 elems per lane)
  float posv = 0.f;
  if (half == 0) {
    const int va = pq[lane];
    const int vb = embQ[(size_t)(base + K_POS - 1) * 64 + lane];
    int d = sb(va, 0) * sb(vb, 0) + sb(va, 1) * sb(vb, 1) +
            sb(va, 2) * sb(vb, 2) + sb(va, 3) * sb(vb, 3);
    float s = (float)d;
    s += __shfl_xor(s, 1);  s += __shfl_xor(s, 2);  s += __shfl_xor(s, 4);
    s += __shfl_xor(s, 8);  s += __shfl_xor(s, 16); s += __shfl_xor(s, 32);
    posv = s * QDESCALE;
  }

  // hoist all 8 tile indices
  const int* nb = neg_perm + (size_t)n * M_NEG + half * 128;
  int idx[8];
#pragma unroll
  for (int jt = 0; jt < 8; ++jt) {
    const int j = nb[jt * 16 + jl];
    idx[jt] = j + (j >= base ? K_POS : 0);
  }

  float m0 = -INFINITY, s0 = 0.f, m1 = -INFINITY, s1 = 0.f;
#pragma unroll
  for (int t = 0; t < 8; t += 2) {
    const int* bp0 = embQ + (size_t)idx[t] * 64 + g * 4;
    const int* bp1 = embQ + (size_t)idx[t + 1] * 64 + g * 4;
    i32x4 acc0 = {0, 0, 0, 0}, acc1 = {0, 0, 0, 0};
#pragma unroll
    for (int kk = 0; kk < 4; ++kk) {
      const i32x4 b0 = *(const i32x4*)(bp0 + kk * 16);
      acc0 = __builtin_amdgcn_mfma_i32_16x16x64_i8(aQ[kk], b0, acc0, 0, 0, 0);
    }
#pragma unroll
    for (int kk = 0; kk < 4; ++kk) {
      const i32x4 b1 = *(const i32x4*)(bp1 + kk * 16);
      acc1 = __builtin_amdgcn_mfma_i32_16x16x64_i8(aQ[kk], b1, acc1, 0, 0, 0);
    }
    const float v0 = (float)acc0[0] * QDESCALE;
    const float v1 = (float)acc1[0] * QDESCALE;
    { const float mn = fmaxf(m0, v0); s0 = s0 * __expf(m0 - mn) + __expf(v0 - mn); m0 = mn; }
    { const float mn = fmaxf(m1, v1); s1 = s1 * __expf(m1 - mn) + __expf(v1 - mn); m1 = mn; }
  }

  // merge chains, then wave reduce (each negative counted by 4 lane-groups -> /4)
  float m = fmaxf(m0, m1);
  float s = s0 * __expf(m0 - m) + s1 * __expf(m1 - m);

  float gm = m;
  gm = fmaxf(gm, __shfl_xor(gm, 1));  gm = fmaxf(gm, __shfl_xor(gm, 2));
  gm = fmaxf(gm, __shfl_xor(gm, 4));  gm = fmaxf(gm, __shfl_xor(gm, 8));
  gm = fmaxf(gm, __shfl_xor(gm, 16)); gm = fmaxf(gm, __shfl_xor(gm, 32));
  float sr = s * __expf(m - gm);
  sr += __shfl_xor(sr, 1);  sr += __shfl_xor(sr, 2);  sr += __shfl_xor(sr, 4);
  sr += __shfl_xor(sr, 8);  sr += __shfl_xor(sr, 16); sr += __shfl_xor(sr, 32);
  sr *= 0.25f;

  if (lane == 0) { smax[wv] = gm; ssum[wv] = sr; spos[wv] = posv; }
  __syncthreads();

  if (half == 0 && lane == 0) {
    const float ma = smax[wv], mb = smax[wv + 1];
    const float sa = ssum[wv], sb2 = ssum[wv + 1];
    const float pv = spos[wv];
    const float mm = fmaxf(fmaxf(ma, mb), pv);
    const float tot = sa * __expf(ma - mm) + sb2 * __expf(mb - mm) + __expf(pv - mm);
    row_loss[n] = __logf(tot) + mm - pv;
  }
}

// ---------------- Kernel 3: deterministic mean (1024 thr, one float4 each) ----------
__global__ __launch_bounds__(1024) void reduce_mean(
    const float* __restrict__ row_loss, float* __restrict__ out) {
  const int tid = threadIdx.x;
  const int lane = tid & 63, wv = tid >> 6;
  const float4 v = ((const float4*)row_loss)[tid];
  float s = v.x + v.y + v.z + v.w;
  s += __shfl_xor(s, 1);  s += __shfl_xor(s, 2);  s += __shfl_xor(s, 4);
  s += __shfl_xor(s, 8);  s += __shfl_xor(s, 16); s += __shfl_xor(s, 32);
  __shared__ float red[16];
  if (lane == 0) red[wv] = s;
  __syncthreads();
  if (tid == 0) {
    float t = 0.f;
#pragma unroll
    for (int i = 0; i < 16; ++i) t += red[i];
    out[0] = t * (1.0f / N_GROUPS);
  }
}

extern "C" void kernel_launch(void* const* d_in, const int* in_sizes, int n_in,
                              void* d_out, int out_size, void* d_ws, size_t ws_size,
                              hipStream_t stream) {
  const float* emb = (const float*)d_in[0];
  const float* W = (const float*)d_in[1];
  const float* b = (const float*)d_in[2];
  const int* neg_perm = (const int*)d_in[4];
  float* out = (float*)d_out;

  int* embQ = (int*)d_ws;                                    // 4.2 MB (i8 packed)
  int* WQ = embQ + (size_t)N_EMB * HID / 4;                  // 0.2 MB
  int* predQ = WQ + (size_t)KDIM * HID / 4;                  // 1.05 MB (i8 packed)
  float* row_loss = (float*)(predQ + (size_t)N_GROUPS * HID / 4);

  const int n4 = N4_EMB + N4_W;
  convert_in<<<(n4 + 255) / 256, 256, 0, stream>>>(emb, W, embQ, WQ);
  gemm_i8<<<dim3(N_GROUPS / 64, 4), 256, 0, stream>>>(embQ, WQ, b, predQ);
  loss_mfma<<<N_GROUPS / 2, 256, 0, stream>>>(embQ, predQ, neg_perm, row_loss);
  reduce_mean<<<1, 1024, 0, stream>>>(row_loss, out);
}